// Round 4
// baseline (353.842 us; speedup 1.0000x reference)
//
#include <hip/hip_runtime.h>
#include <stdint.h>

// MeshPoolFace: batched segment-mean pooling.
// fe: [B=16, C=256, F=16000] f32, gid: [B, F] int32 in [0, T=8000)
// out[b][c][t] = mean over {f : gid[b][f]==t} of fe[b][c][f]
//
// Round-11: scatter-add rewrite. Avg group size = 16000/8000 = 2, so the
// sort-gather structure (K2 scan/rank + K3 invperm + scatter-b16 + dependent
// scalar gather loop) was all overhead: pool ~94us vs 63us traffic floor,
// preprocessing ~28us. New pool: ds_add_f32 directly at gid (register-cached
// once, reused x8 channels), double-buffered acc (2x32KB) -> ONE barrier per
// channel, flush(prev buf) overlaps scatter(cur buf) in the same window.
// Preprocessing is now just memset+hist (counts -> reciprocals, cached once).
// f32 accumulation (no bf16 conversion VALU at all).

#define NB 16
#define NC 256
#define NF 16000
#define NT 8000
#define CPB 8   // channels per pool block; grid = NB * NC/CPB = 512

typedef unsigned int uint;
typedef unsigned short ushort;
typedef float f32x4 __attribute__((ext_vector_type(4)));

// K1: global histogram of group sizes. grid = 250.
__global__ __launch_bounds__(256) void hist_kernel(const int* __restrict__ gid,
                                                   int* __restrict__ cnt) {
    int i = blockIdx.x * 256 + threadIdx.x;
    if (i >= NB * NF / 4) return;
    int4 g = ((const int4*)gid)[i];
    int* c = cnt + (i / (NF / 4)) * NT;
    atomicAdd(&c[g.x], 1);
    atomicAdd(&c[g.y], 1);
    atomicAdd(&c[g.z], 1);
    atomicAdd(&c[g.w], 1);
}

__device__ __forceinline__ void ds_addf(uint addr, float v) {
    asm volatile("ds_add_f32 %0, %1" :: "v"(addr), "v"(v));
}
__device__ __forceinline__ void ds_addf_hi(uint addr, float v) {
    asm volatile("ds_add_f32 %0, %1 offset:32768" :: "v"(addr), "v"(v));
}

// K4: scatter-add pool. grid = NB*(NC/CPB) = 512 blocks, 1024 thr,
// 64 KB LDS (acc double buffer). Per channel: scatter(16 ds_add_f32) ->
// prefetch k+1 -> lgkm drain + barrier -> flush+zero (overlaps next scatter
// across waves). One barrier per channel.
__global__ __launch_bounds__(1024) void pool_kernel(const float* __restrict__ fe,
                                                    const int* __restrict__ gid,
                                                    const int* __restrict__ cnt,
                                                    float* __restrict__ out) {
    __shared__ float acc[2][8192];   // 2 x 32768 B (8000 used + pad)
    const int bid = blockIdx.x;
    const int b = bid >> 5, cg = bid & 31;
    const int tid = threadIdx.x;
    const size_t bc0 = (size_t)(b * NC + cg * CPB);
    const bool t3 = (tid < 928);     // face-range tail (4000 f32x4 total)
    const bool tc = (tid < 976);     // out-range tail (2000 f32x4 total)

    // zero both acc buffers: 4096 f32x4 / 1024 threads = 4 each.
    {
        f32x4* az = (f32x4*)&acc[0][0];
        f32x4 z = (f32x4)(0.f);
        az[tid] = z;
        az[tid + 1024] = z;
        az[tid + 2048] = z;
        az[tid + 3072] = z;
    }

    // Register-cache gid for this thread's 16 faces as packed byte-offsets
    // (4*g fits 16 bits). Face order matches the fe f32x4 loads below.
    const int4* g4 = (const int4*)(gid + (size_t)b * NF);
    int4 ga = g4[tid];
    int4 gb4 = g4[tid + 1024];
    int4 gc = g4[tid + 2048];
    int4 gd = make_int4(0, 0, 0, 0);
    if (t3) gd = g4[tid + 3072];
    const uint p0 = ((uint)ga.x << 2) | ((uint)ga.y << 18);
    const uint p1 = ((uint)ga.z << 2) | ((uint)ga.w << 18);
    const uint p2 = ((uint)gb4.x << 2) | ((uint)gb4.y << 18);
    const uint p3 = ((uint)gb4.z << 2) | ((uint)gb4.w << 18);
    const uint p4 = ((uint)gc.x << 2) | ((uint)gc.y << 18);
    const uint p5 = ((uint)gc.z << 2) | ((uint)gc.w << 18);
    const uint p6 = ((uint)gd.x << 2) | ((uint)gd.y << 18);
    const uint p7 = ((uint)gd.z << 2) | ((uint)gd.w << 18);
    const uint accb = (uint)(uintptr_t)&acc[0][0];

    // Register-cache count reciprocals for this thread's 8 output slots
    // (f32x4 indices tid and tid+1024(<976)).
    const int4* c4 = (const int4*)(cnt + (size_t)b * NT);
    f32x4 ra, rb;
    {
        int4 ca = c4[tid];
        ra[0] = ca.x ? __builtin_amdgcn_rcpf((float)ca.x) : 0.f;
        ra[1] = ca.y ? __builtin_amdgcn_rcpf((float)ca.y) : 0.f;
        ra[2] = ca.z ? __builtin_amdgcn_rcpf((float)ca.z) : 0.f;
        ra[3] = ca.w ? __builtin_amdgcn_rcpf((float)ca.w) : 0.f;
        rb = (f32x4)(0.f);
        if (tc) {
            int4 cb = c4[tid + 1024];
            rb[0] = cb.x ? __builtin_amdgcn_rcpf((float)cb.x) : 0.f;
            rb[1] = cb.y ? __builtin_amdgcn_rcpf((float)cb.y) : 0.f;
            rb[2] = cb.z ? __builtin_amdgcn_rcpf((float)cb.z) : 0.f;
            rb[3] = cb.w ? __builtin_amdgcn_rcpf((float)cb.w) : 0.f;
        }
    }

    const f32x4* fe4base = (const f32x4*)(fe + bc0 * NF);
    f32x4 n0, n1, n2, n3;
    n3 = (f32x4)(0.f);
    {
        const f32x4* f4 = fe4base;
        n0 = __builtin_nontemporal_load(&f4[tid]);
        n1 = __builtin_nontemporal_load(&f4[tid + 1024]);
        n2 = __builtin_nontemporal_load(&f4[tid + 2048]);
        if (t3) n3 = __builtin_nontemporal_load(&f4[tid + 3072]);
    }
    __syncthreads();   // zeros visible

#define SCAT4(HI, PA, PB, V) do {                                       \
        uint a0_ = accb + ((PA) & 0xFFFFu);                             \
        uint a1_ = accb + ((PA) >> 16);                                 \
        uint a2_ = accb + ((PB) & 0xFFFFu);                             \
        uint a3_ = accb + ((PB) >> 16);                                 \
        if (HI) {                                                       \
            ds_addf_hi(a0_, (V)[0]); ds_addf_hi(a1_, (V)[1]);           \
            ds_addf_hi(a2_, (V)[2]); ds_addf_hi(a3_, (V)[3]);           \
        } else {                                                        \
            ds_addf(a0_, (V)[0]); ds_addf(a1_, (V)[1]);                 \
            ds_addf(a2_, (V)[2]); ds_addf(a3_, (V)[3]);                 \
        }                                                               \
    } while (0)

#pragma unroll
    for (int k = 0; k < CPB; ++k) {
        const int hi = k & 1;
        // scatter channel k into acc[hi]
        SCAT4(hi, p0, p1, n0);
        SCAT4(hi, p2, p3, n1);
        SCAT4(hi, p4, p5, n2);
        if (t3) SCAT4(hi, p6, p7, n3);

        // issue channel k+1 loads: in flight across barrier + flush
        if (k + 1 < CPB) {
            const f32x4* f4 = fe4base + (size_t)(k + 1) * (NF / 4);
            n0 = __builtin_nontemporal_load(&f4[tid]);
            n1 = __builtin_nontemporal_load(&f4[tid + 1024]);
            n2 = __builtin_nontemporal_load(&f4[tid + 2048]);
            if (t3) n3 = __builtin_nontemporal_load(&f4[tid + 3072]);
        }

        asm volatile("s_waitcnt lgkmcnt(0)" ::: "memory");
        __syncthreads();   // scatter(k) complete; flush may read acc[hi]

        // flush+zero acc[hi] -> out row k (coalesced nontemporal f32x4).
        // Next scatter (k+1) targets acc[!hi]; its previous flush-zero was
        // ordered before the barrier above.
        {
            f32x4* ab = (f32x4*)&acc[hi][0];
            f32x4* o4 = (f32x4*)(out + (bc0 + (size_t)k) * NT);
            f32x4 v = ab[tid];
            v *= ra;
            __builtin_nontemporal_store(v, &o4[tid]);
            ab[tid] = (f32x4)(0.f);
            if (tc) {
                f32x4 w = ab[tid + 1024];
                w *= rb;
                __builtin_nontemporal_store(w, &o4[tid + 1024]);
                ab[tid + 1024] = (f32x4)(0.f);
            }
        }
    }
#undef SCAT4
}

// Fallback (round-2 path) if workspace is too small.
__device__ __forceinline__ void lds_fadd(unsigned addr, float v) {
    asm volatile("ds_add_f32 %0, %1" :: "v"(addr), "v"(v));
}
__global__ __launch_bounds__(256) void pool_fused_kernel(const float* __restrict__ fe,
                                                         const int* __restrict__ gid,
                                                         float* __restrict__ out) {
    __shared__ float acc[NT];
    __shared__ int cnt[NT];
    const int bc = blockIdx.x, b = bc >> 8, tid = threadIdx.x;
    for (int t = tid; t < NT; t += 256) { acc[t] = 0.0f; cnt[t] = 0; }
    __syncthreads();
    const unsigned accb = (unsigned)(uintptr_t)acc;
    const float4* fe4 = (const float4*)(fe + (size_t)bc * NF);
    const int4* gid4 = (const int4*)(gid + (size_t)b * NF);
    for (int i = tid; i < NF / 4; i += 256) {
        float4 v = fe4[i];
        int4 g = gid4[i];
        lds_fadd(accb + 4u * (unsigned)g.x, v.x); atomicAdd(&cnt[g.x], 1);
        lds_fadd(accb + 4u * (unsigned)g.y, v.y); atomicAdd(&cnt[g.y], 1);
        lds_fadd(accb + 4u * (unsigned)g.z, v.z); atomicAdd(&cnt[g.z], 1);
        lds_fadd(accb + 4u * (unsigned)g.w, v.w); atomicAdd(&cnt[g.w], 1);
    }
    asm volatile("s_waitcnt lgkmcnt(0)" ::: "memory");
    __syncthreads();
    float* orow = out + (size_t)bc * NT;
    for (int t = tid; t < NT; t += 256) {
        int n = cnt[t];
        orow[t] = acc[t] / (float)(n > 0 ? n : 1);
    }
}

extern "C" void kernel_launch(void* const* d_in, const int* in_sizes, int n_in,
                              void* d_out, int out_size, void* d_ws, size_t ws_size,
                              hipStream_t stream) {
    const float* fe = (const float*)d_in[0];
    const int* gid = (const int*)d_in[1];
    float* out = (float*)d_out;

    // workspace: cnt only — int [NB*NT] = 512000 bytes
    if (ws_size >= 512000) {
        int* cnt = (int*)d_ws;
        (void)hipMemsetAsync(cnt, 0, 512000, stream);
        hist_kernel<<<(NB * NF / 4 + 255) / 256, 256, 0, stream>>>(gid, cnt);
        pool_kernel<<<NB * (NC / CPB), 1024, 0, stream>>>(fe, gid, cnt, out);
    } else {
        pool_fused_kernel<<<NB * NC, 256, 0, stream>>>(fe, gid, out);
    }
}

// Round 5
// 118.762 us; speedup vs baseline: 2.9794x; 2.9794x over previous
//
#include <hip/hip_runtime.h>
#include <stdint.h>

// MeshPoolFace: batched segment-mean pooling.
// fe: [B=16, C=256, F=16000] f32, gid: [B, F] int32 in [0, T=8000)
// out[b][c][t] = mean over {f : gid[b][f]==t} of fe[b][c][f]
//
// Round-12: channel-PAIR packing. Round-11 falsified scatter-add (LDS f32
// atomics ~3.2 cyc/lane -> 337us, VALUBusy 0.6%). Back to round-10's
// sort-gather pipeline (122us champion), but amortize the shared index
// structure across 2 channels per LDS word:
//   - v_cvt_pk_bf16_f32 packs (ch0,ch1) -> one u32, one ds_write_b32
//   - one ds_read_b32 in the gather yields BOTH channels
//   - per-channel LDS ops, conversion VALU, and barriers all halve
//   - 128 KB dynamic LDS (fes32 64K + outs 2ch 64K), opt-in, 1 block/CU
//   - raw s_barrier + lgkmcnt(0) only (no vmcnt drain at barriers) so the
//     depth-1 prefetch of the next channel pair stays in flight across
//     P1 + flush
// CPB=16 channels/block, grid = NB*NC/16 = 256 = 1 block/CU.

#define NB 16
#define NC 256
#define NF 16000
#define NT 8000
#define CPB 16  // channels per pool block (8 pairs); grid = NB*NC/CPB = 256

typedef unsigned int uint;
typedef unsigned short ushort;
typedef float f32x4 __attribute__((ext_vector_type(4)));

__device__ __forceinline__ float bf2f(uint h) { return __uint_as_float(h << 16); }
__device__ __forceinline__ uint cvtpk(float lo, float hi) {
    uint r;
    asm("v_cvt_pk_bf16_f32 %0, %1, %2" : "=v"(r) : "v"(lo), "v"(hi));
    return r;
}
__device__ __forceinline__ uint bf16rne(float x) {
    uint u = __float_as_uint(x);
    return (u + 0x7FFFu + ((u >> 16) & 1u)) >> 16;
}

// K1: global histogram of group sizes. grid = 250.
__global__ __launch_bounds__(256) void hist_kernel(const int* __restrict__ gid,
                                                   int* __restrict__ cnt) {
    int i = blockIdx.x * 256 + threadIdx.x;
    if (i >= NB * NF / 4) return;
    int4 g = ((const int4*)gid)[i];
    int* c = cnt + (i / (NF / 4)) * NT;
    atomicAdd(&c[g.x], 1);
    atomicAdd(&c[g.y], 1);
    atomicAdd(&c[g.z], 1);
    atomicAdd(&c[g.w], 1);
}

// K2: per batch (grid=NB): exclusive scan of cnt -> off; size-sorted rank
// order: gorder (rank->t), pk (rank -> off | n<<14); cursor = off copy.
__global__ __launch_bounds__(256) void scan_rank_kernel(const int* __restrict__ cnt_g,
                                                        uint* __restrict__ pk,
                                                        uint* __restrict__ cursor,
                                                        ushort* __restrict__ gorder) {
    __shared__ int off_s[NT];
    __shared__ int partial[256];
    __shared__ int hist2[65];
    __shared__ int cur2[65];
    const int b = blockIdx.x, tid = threadIdx.x;
    const int* cnt = cnt_g + b * NT;

    int loc[32];
    int ts = 0;
    if (tid < 250) {
        const int4* c4 = (const int4*)(cnt + 32 * tid);
#pragma unroll
        for (int j = 0; j < 8; ++j) {
            int4 v = c4[j];
            loc[4 * j + 0] = ts; ts += v.x;
            loc[4 * j + 1] = ts; ts += v.y;
            loc[4 * j + 2] = ts; ts += v.z;
            loc[4 * j + 3] = ts; ts += v.w;
        }
    }
    partial[tid] = (tid < 250) ? ts : 0;
    if (tid < 65) hist2[tid] = 0;
    __syncthreads();

    if (tid < 64) {
        int s0 = partial[4 * tid], s1 = partial[4 * tid + 1];
        int s2 = partial[4 * tid + 2], s3 = partial[4 * tid + 3];
        int lsum = s0 + s1 + s2 + s3;
        int inc = lsum;
        for (int d = 1; d < 64; d <<= 1) {
            int u = __shfl_up(inc, d);
            if (tid >= d) inc += u;
        }
        int exc = inc - lsum;
        partial[4 * tid + 0] = exc;
        partial[4 * tid + 1] = exc + s0;
        partial[4 * tid + 2] = exc + s0 + s1;
        partial[4 * tid + 3] = exc + s0 + s1 + s2;
    }
    __syncthreads();

    if (tid < 250) {
        int base = partial[tid];
#pragma unroll
        for (int j = 0; j < 32; ++j) off_s[32 * tid + j] = base + loc[j];
    }
    __syncthreads();

    for (int t = tid; t < NT; t += 256) {
        int n = cnt[t];
        atomicAdd(&hist2[n > 64 ? 64 : n], 1);
    }
    __syncthreads();
    if (tid == 0) {
        int s = 0;
        for (int i = 0; i < 65; ++i) { int h = hist2[i]; cur2[i] = s; s += h; }
    }
    __syncthreads();

    uint* pkb = pk + (size_t)b * NT;
    uint* cb = cursor + (size_t)b * NT;
    ushort* gb = gorder + (size_t)b * NT;
    for (int t = tid; t < NT; t += 256) {
        int n = cnt[t];
        int o = off_s[t];
        int rnk = atomicAdd(&cur2[n > 64 ? 64 : n], 1);
        gb[rnk] = (ushort)t;
        pkb[rnk] = (uint)o | ((uint)n << 14);      // off < 16384, n < 2^18
        cb[t] = (uint)o;
    }
}

// K3: compute INVERSE permutation sp[b][f] = sorted position of face f.
__global__ __launch_bounds__(256) void invperm_kernel(const int* __restrict__ gid,
                                                      uint* __restrict__ cursor,
                                                      ushort* __restrict__ sp) {
    const int b = blockIdx.x >> 2, q = blockIdx.x & 3;
    const int4* g4 = (const int4*)(gid + (size_t)b * NF + q * (NF / 4));
    uint* cb = cursor + (size_t)b * NT;
    uint2* sp2 = (uint2*)(sp + (size_t)b * NF + q * (NF / 4));  // 8B aligned
    for (int i = threadIdx.x; i < NF / 16; i += 256) {
        int4 g = g4[i];
        uint p0 = atomicAdd(&cb[g.x], 1u);
        uint p1 = atomicAdd(&cb[g.y], 1u);
        uint p2 = atomicAdd(&cb[g.z], 1u);
        uint p3 = atomicAdd(&cb[g.w], 1u);
        sp2[i] = make_uint2(p0 | (p1 << 16), p2 | (p3 << 16));
    }
}

// Raw barrier: drain own LDS ops, workgroup barrier. Never drains vmcnt,
// so global prefetch loads stay in flight across it.
#define LGKM_BAR() do {                                          \
        asm volatile("s_waitcnt lgkmcnt(0)" ::: "memory");       \
        __builtin_amdgcn_s_barrier();                            \
        __builtin_amdgcn_sched_barrier(0);                       \
    } while (0)

// K4: pair-packed pool. grid = 256, 1024 thr, 128000 B dynamic LDS.
// Per pair: WRITE(16 cvt_pk + 16 ds_write_b32) / bar / prefetch + P1
// (gather b32 -> 2ch sums -> outs x2) / bar / FLUSH (2 coalesced rows).
__global__ __launch_bounds__(1024) void pool_kernel(const float* __restrict__ fe,
                                                    const ushort* __restrict__ sp,
                                                    const uint* __restrict__ pk,
                                                    const ushort* __restrict__ gorder,
                                                    float* __restrict__ out) {
    extern __shared__ char smem[];
    uint* fes32 = (uint*)smem;                    // 64000 B: packed 2ch bf16
    float* outs = (float*)(smem + 64000);         // 64000 B: 2ch means
    const int bid = blockIdx.x;
    const int b = bid >> 4, cg = bid & 15;
    const int tid = threadIdx.x;
    const size_t bc0 = (size_t)(b * NC + cg * CPB);
    const bool t3 = (tid < 928);     // face tail: 4000 f32x4 per channel
    const bool tc = (tid < 976);     // out tail: 2000 f32x4 per channel
    const bool t8 = (tid < 832);     // rank tail: 8000 ranks

    // Register-cache inverse permutation (slot indices, packed u16 pairs)
    const uint2* sp2 = (const uint2*)(sp + (size_t)b * NF);
    uint2 s0 = sp2[tid];
    uint2 s1 = sp2[tid + 1024];
    uint2 s2 = sp2[tid + 2048];
    uint2 s3 = make_uint2(0u, 0u);
    if (t3) s3 = sp2[tid + 3072];

    // Register-cache pk/gorder (ranks {tid+it*1024, it<7} + {7168+tid,<832})
    const uint* pkb = pk + (size_t)b * NT;
    const ushort* gob = gorder + (size_t)b * NT;
    uint pv[8];
    ushort gv[8];
#pragma unroll
    for (int it = 0; it < 7; ++it) {
        pv[it] = pkb[tid + it * 1024];
        gv[it] = gob[tid + it * 1024];
    }
    pv[7] = 0; gv[7] = 0;
    if (t8) { pv[7] = pkb[7168 + tid]; gv[7] = gob[7168 + tid]; }

    const f32x4* fe4base = (const f32x4*)(fe + bc0 * NF);
    f32x4 a0, a1, a2, a3, b0, b1, b2, b3;
    a3 = (f32x4)(0.f); b3 = (f32x4)(0.f);

    // prologue: issue pair-0 loads (channels 0,1)
    {
        const f32x4* fA = fe4base;
        const f32x4* fB = fe4base + (NF / 4);
        a0 = __builtin_nontemporal_load(&fA[tid]);
        a1 = __builtin_nontemporal_load(&fA[tid + 1024]);
        a2 = __builtin_nontemporal_load(&fA[tid + 2048]);
        if (t3) a3 = __builtin_nontemporal_load(&fA[tid + 3072]);
        b0 = __builtin_nontemporal_load(&fB[tid]);
        b1 = __builtin_nontemporal_load(&fB[tid + 1024]);
        b2 = __builtin_nontemporal_load(&fB[tid + 2048]);
        if (t3) b3 = __builtin_nontemporal_load(&fB[tid + 3072]);
    }

#define PAIR_WRITE(S, VA, VB) do {                                       \
        fes32[(S).x & 0xFFFFu] = cvtpk((VA)[0], (VB)[0]);                \
        fes32[(S).x >> 16]     = cvtpk((VA)[1], (VB)[1]);                \
        fes32[(S).y & 0xFFFFu] = cvtpk((VA)[2], (VB)[2]);                \
        fes32[(S).y >> 16]     = cvtpk((VA)[3], (VB)[3]);                \
    } while (0)

#pragma unroll
    for (int k = 0; k < CPB / 2; ++k) {
        // WRITE: consume current pair regs (compiler inserts vmcnt waits)
        PAIR_WRITE(s0, a0, b0);
        PAIR_WRITE(s1, a1, b1);
        PAIR_WRITE(s2, a2, b2);
        if (t3) PAIR_WRITE(s3, a3, b3);

        // prefetch next pair: in flight across bar + P1 + bar + flush
        if (k + 1 < CPB / 2) {
            const f32x4* fA = fe4base + (size_t)(2 * k + 2) * (NF / 4);
            const f32x4* fB = fA + (NF / 4);
            a0 = __builtin_nontemporal_load(&fA[tid]);
            a1 = __builtin_nontemporal_load(&fA[tid + 1024]);
            a2 = __builtin_nontemporal_load(&fA[tid + 2048]);
            if (t3) a3 = __builtin_nontemporal_load(&fA[tid + 3072]);
            b0 = __builtin_nontemporal_load(&fB[tid]);
            b1 = __builtin_nontemporal_load(&fB[tid + 1024]);
            b2 = __builtin_nontemporal_load(&fB[tid + 2048]);
            if (t3) b3 = __builtin_nontemporal_load(&fB[tid + 3072]);
        }

        LGKM_BAR();   // fes32 ready

        // P1: gather both channels per rank; scatter means to outs.
#pragma unroll
        for (int it = 0; it < 7; ++it) {
            uint p = pv[it];
            uint off = p & 0x3FFFu, n = p >> 14;
            float sa = 0.f, sb = 0.f;
            for (uint r = 0; r < n; ++r) {
                uint w = fes32[off + r];
                sa += bf2f(w & 0xFFFFu);
                sb += bf2f(w >> 16);
            }
            float rn = n ? __builtin_amdgcn_rcpf((float)n) : 0.f;
            outs[gv[it]] = sa * rn;
            outs[NT + gv[it]] = sb * rn;
        }
        if (t8) {
            uint p = pv[7];
            uint off = p & 0x3FFFu, n = p >> 14;
            float sa = 0.f, sb = 0.f;
            for (uint r = 0; r < n; ++r) {
                uint w = fes32[off + r];
                sa += bf2f(w & 0xFFFFu);
                sb += bf2f(w >> 16);
            }
            float rn = n ? __builtin_amdgcn_rcpf((float)n) : 0.f;
            outs[gv[7]] = sa * rn;
            outs[NT + gv[7]] = sb * rn;
        }

        LGKM_BAR();   // outs ready; fes32 fully consumed

        // FLUSH: coalesced nontemporal f32x4, both channels
        {
            const f32x4* oa = (const f32x4*)outs;
            const f32x4* ob = (const f32x4*)(outs + NT);
            f32x4* oA = (f32x4*)(out + (bc0 + (size_t)(2 * k)) * NT);
            f32x4* oB = (f32x4*)(out + (bc0 + (size_t)(2 * k + 1)) * NT);
            __builtin_nontemporal_store(oa[tid], &oA[tid]);
            __builtin_nontemporal_store(ob[tid], &oB[tid]);
            if (tc) {
                __builtin_nontemporal_store(oa[1024 + tid], &oA[1024 + tid]);
                __builtin_nontemporal_store(ob[1024 + tid], &oB[1024 + tid]);
            }
        }
    }
#undef PAIR_WRITE
}

// Fallback (round-2 path) if workspace is too small.
__device__ __forceinline__ void lds_fadd(unsigned addr, float v) {
    asm volatile("ds_add_f32 %0, %1" :: "v"(addr), "v"(v));
}
__global__ __launch_bounds__(256) void pool_fused_kernel(const float* __restrict__ fe,
                                                         const int* __restrict__ gid,
                                                         float* __restrict__ out) {
    __shared__ float acc[NT];
    __shared__ int cnt[NT];
    const int bc = blockIdx.x, b = bc >> 8, tid = threadIdx.x;
    for (int t = tid; t < NT; t += 256) { acc[t] = 0.0f; cnt[t] = 0; }
    __syncthreads();
    const unsigned accb = (unsigned)(uintptr_t)acc;
    const float4* fe4 = (const float4*)(fe + (size_t)bc * NF);
    const int4* gid4 = (const int4*)(gid + (size_t)b * NF);
    for (int i = tid; i < NF / 4; i += 256) {
        float4 v = fe4[i];
        int4 g = gid4[i];
        lds_fadd(accb + 4u * (unsigned)g.x, v.x); atomicAdd(&cnt[g.x], 1);
        lds_fadd(accb + 4u * (unsigned)g.y, v.y); atomicAdd(&cnt[g.y], 1);
        lds_fadd(accb + 4u * (unsigned)g.z, v.z); atomicAdd(&cnt[g.z], 1);
        lds_fadd(accb + 4u * (unsigned)g.w, v.w); atomicAdd(&cnt[g.w], 1);
    }
    asm volatile("s_waitcnt lgkmcnt(0)" ::: "memory");
    __syncthreads();
    float* orow = out + (size_t)bc * NT;
    for (int t = tid; t < NT; t += 256) {
        int n = cnt[t];
        orow[t] = acc[t] / (float)(n > 0 ? n : 1);
    }
}

extern "C" void kernel_launch(void* const* d_in, const int* in_sizes, int n_in,
                              void* d_out, int out_size, void* d_ws, size_t ws_size,
                              hipStream_t stream) {
    const float* fe = (const float*)d_in[0];
    const int* gid = (const int*)d_in[1];
    float* out = (float*)d_out;

    // workspace layout (bytes)
    const size_t O_CNT = 0;          // int [NB*NT]   512000
    const size_t O_CUR = 512000;     // u32 [NB*NT]   512000
    const size_t O_PK  = 1024000;    // u32 [NB*NT]   512000
    const size_t O_GO  = 1536000;    // u16 [NB*NT]   256000
    const size_t O_SP  = 1792000;    // u16 [NB*NF]   512000
    const size_t TOTAL = 2304000;

    if (ws_size >= TOTAL) {
        char* w = (char*)d_ws;
        int* cnt = (int*)(w + O_CNT);
        uint* cursor = (uint*)(w + O_CUR);
        uint* pk = (uint*)(w + O_PK);
        ushort* gorder = (ushort*)(w + O_GO);
        ushort* sp = (ushort*)(w + O_SP);

        static bool lds_opted = false;
        if (!lds_opted) {
            (void)hipFuncSetAttribute((const void*)pool_kernel,
                                      hipFuncAttributeMaxDynamicSharedMemorySize,
                                      128000);
            lds_opted = true;
        }

        (void)hipMemsetAsync(cnt, 0, 512000, stream);
        hist_kernel<<<(NB * NF / 4 + 255) / 256, 256, 0, stream>>>(gid, cnt);
        scan_rank_kernel<<<NB, 256, 0, stream>>>(cnt, pk, cursor, gorder);
        invperm_kernel<<<NB * 4, 256, 0, stream>>>(gid, cursor, sp);
        pool_kernel<<<NB * (NC / CPB), 1024, 128000, stream>>>(fe, sp, pk, gorder, out);
    } else {
        pool_fused_kernel<<<NB * NC, 256, 0, stream>>>(fe, gid, out);
    }
}

// Round 6
// 113.501 us; speedup vs baseline: 3.1175x; 1.0464x over previous
//
#include <hip/hip_runtime.h>
#include <stdint.h>

// MeshPoolFace: batched segment-mean pooling.
// fe: [B=16, C=256, F=16000] f32, gid: [B, F] int32 in [0, T=8000)
// out[b][c][t] = mean over {f : gid[b][f]==t} of fe[b][c][f]
//
// Round-13: keep round-12's pair-packed sort-gather pipeline (118.8us), fix
// the window overheads:
//  - UNIFORM vmem counts (8 loads + 4 stores per thread, every window):
//    dummy-address loads for the t3 tail; tail threads re-store element 0
//    (idempotent, same bytes) -> compiler emits precise progressive vmcnt
//    instead of conservative drains; flush stores stay in flight.
//  - plain loads (exploit ~50% L3-resident fe; r11 FETCH=134MB evidence),
//    nontemporal stores only (write-once out stream).
//  - paired gather: 8-byte LDS reads via __builtin_memcpy (ds_read2_b32):
//    one lgkm op = 2 members x 2 channels; avg n=2 -> 1 read per rank.
//  - invperm widened to 256 blocks (atomic-latency-bound).

#define NB 16
#define NC 256
#define NF 16000
#define NT 8000
#define CPB 16  // channels per pool block (8 pairs); grid = NB*NC/CPB = 256

typedef unsigned int uint;
typedef unsigned short ushort;
typedef float f32x4 __attribute__((ext_vector_type(4)));

__device__ __forceinline__ float bf2f(uint h) { return __uint_as_float(h << 16); }
__device__ __forceinline__ uint cvtpk(float lo, float hi) {
    uint r;
    asm("v_cvt_pk_bf16_f32 %0, %1, %2" : "=v"(r) : "v"(lo), "v"(hi));
    return r;
}

// K1: global histogram of group sizes. grid = 250.
__global__ __launch_bounds__(256) void hist_kernel(const int* __restrict__ gid,
                                                   int* __restrict__ cnt) {
    int i = blockIdx.x * 256 + threadIdx.x;
    if (i >= NB * NF / 4) return;
    int4 g = ((const int4*)gid)[i];
    int* c = cnt + (i / (NF / 4)) * NT;
    atomicAdd(&c[g.x], 1);
    atomicAdd(&c[g.y], 1);
    atomicAdd(&c[g.z], 1);
    atomicAdd(&c[g.w], 1);
}

// K2: per batch (grid=NB): exclusive scan of cnt -> off; size-sorted rank
// order: gorder (rank->t), pk (rank -> off | n<<14); cursor = off copy.
__global__ __launch_bounds__(256) void scan_rank_kernel(const int* __restrict__ cnt_g,
                                                        uint* __restrict__ pk,
                                                        uint* __restrict__ cursor,
                                                        ushort* __restrict__ gorder) {
    __shared__ int off_s[NT];
    __shared__ int partial[256];
    __shared__ int hist2[65];
    __shared__ int cur2[65];
    const int b = blockIdx.x, tid = threadIdx.x;
    const int* cnt = cnt_g + b * NT;

    int loc[32];
    int ts = 0;
    if (tid < 250) {
        const int4* c4 = (const int4*)(cnt + 32 * tid);
#pragma unroll
        for (int j = 0; j < 8; ++j) {
            int4 v = c4[j];
            loc[4 * j + 0] = ts; ts += v.x;
            loc[4 * j + 1] = ts; ts += v.y;
            loc[4 * j + 2] = ts; ts += v.z;
            loc[4 * j + 3] = ts; ts += v.w;
        }
    }
    partial[tid] = (tid < 250) ? ts : 0;
    if (tid < 65) hist2[tid] = 0;
    __syncthreads();

    if (tid < 64) {
        int s0 = partial[4 * tid], s1 = partial[4 * tid + 1];
        int s2 = partial[4 * tid + 2], s3 = partial[4 * tid + 3];
        int lsum = s0 + s1 + s2 + s3;
        int inc = lsum;
        for (int d = 1; d < 64; d <<= 1) {
            int u = __shfl_up(inc, d);
            if (tid >= d) inc += u;
        }
        int exc = inc - lsum;
        partial[4 * tid + 0] = exc;
        partial[4 * tid + 1] = exc + s0;
        partial[4 * tid + 2] = exc + s0 + s1;
        partial[4 * tid + 3] = exc + s0 + s1 + s2;
    }
    __syncthreads();

    if (tid < 250) {
        int base = partial[tid];
#pragma unroll
        for (int j = 0; j < 32; ++j) off_s[32 * tid + j] = base + loc[j];
    }
    __syncthreads();

    for (int t = tid; t < NT; t += 256) {
        int n = cnt[t];
        atomicAdd(&hist2[n > 64 ? 64 : n], 1);
    }
    __syncthreads();
    if (tid == 0) {
        int s = 0;
        for (int i = 0; i < 65; ++i) { int h = hist2[i]; cur2[i] = s; s += h; }
    }
    __syncthreads();

    uint* pkb = pk + (size_t)b * NT;
    uint* cb = cursor + (size_t)b * NT;
    ushort* gb = gorder + (size_t)b * NT;
    for (int t = tid; t < NT; t += 256) {
        int n = cnt[t];
        int o = off_s[t];
        int rnk = atomicAdd(&cur2[n > 64 ? 64 : n], 1);
        gb[rnk] = (ushort)t;
        pkb[rnk] = (uint)o | ((uint)n << 14);      // off < 16384, n < 2^18
        cb[t] = (uint)o;
    }
}

// K3: INVERSE permutation sp[b][f] = sorted position of face f.
// grid = NB*16 (widened: atomic-latency-bound).
__global__ __launch_bounds__(256) void invperm_kernel(const int* __restrict__ gid,
                                                      uint* __restrict__ cursor,
                                                      ushort* __restrict__ sp) {
    const int b = blockIdx.x >> 4, q = blockIdx.x & 15;
    const int tid = threadIdx.x;
    if (tid >= 250) return;
    const int4* g4 = (const int4*)(gid + (size_t)b * NF + q * 1000);
    uint* cb = cursor + (size_t)b * NT;
    uint2* sp2 = (uint2*)(sp + (size_t)b * NF + q * 1000);  // 8B aligned
    int4 g = g4[tid];
    uint p0 = atomicAdd(&cb[g.x], 1u);
    uint p1 = atomicAdd(&cb[g.y], 1u);
    uint p2 = atomicAdd(&cb[g.z], 1u);
    uint p3 = atomicAdd(&cb[g.w], 1u);
    sp2[tid] = make_uint2(p0 | (p1 << 16), p2 | (p3 << 16));
}

// Raw barrier: drain own LDS ops, workgroup barrier. Never drains vmcnt,
// so global prefetch loads / NT stores stay in flight across it.
#define LGKM_BAR() do {                                          \
        asm volatile("s_waitcnt lgkmcnt(0)" ::: "memory");       \
        __builtin_amdgcn_s_barrier();                            \
        __builtin_amdgcn_sched_barrier(0);                       \
    } while (0)

// K4: pair-packed pool. grid = 256, 1024 thr, 128000 B dynamic LDS.
__global__ __launch_bounds__(1024) void pool_kernel(const float* __restrict__ fe,
                                                    const ushort* __restrict__ sp,
                                                    const uint* __restrict__ pk,
                                                    const ushort* __restrict__ gorder,
                                                    float* __restrict__ out) {
    extern __shared__ char smem[];
    uint* fes32 = (uint*)smem;                    // 64000 B: packed 2ch bf16
    float* outs = (float*)(smem + 64000);         // 64000 B: 2ch means
    const int bid = blockIdx.x;
    const int b = bid >> 4, cg = bid & 15;
    const int tid = threadIdx.x;
    const size_t bc0 = (size_t)(b * NC + cg * CPB);
    const bool t3 = (tid < 928);     // face tail: 4000 f32x4 per channel
    const bool tc = (tid < 976);     // out tail: 2000 f32x4 per channel
    const bool t8 = (tid < 832);     // rank tail: 8000 ranks
    const int tl = t3 ? tid + 3072 : tid;   // uniform-load index (dummy=tid)
    const int fi = tc ? tid + 1024 : 0;     // uniform-store index (dummy=0)

    // Register-cache inverse permutation (slot indices, packed u16 pairs)
    const uint2* sp2 = (const uint2*)(sp + (size_t)b * NF);
    uint2 s0 = sp2[tid];
    uint2 s1 = sp2[tid + 1024];
    uint2 s2 = sp2[tid + 2048];
    uint2 s3 = sp2[tl];   // garbage for !t3, never written

    // Register-cache pk/gorder (ranks {tid+it*1024, it<7} + {7168+tid,<832})
    const uint* pkb = pk + (size_t)b * NT;
    const ushort* gob = gorder + (size_t)b * NT;
    uint pv[8];
    ushort gv[8];
#pragma unroll
    for (int it = 0; it < 7; ++it) {
        pv[it] = pkb[tid + it * 1024];
        gv[it] = gob[tid + it * 1024];
    }
    pv[7] = 0; gv[7] = 0;
    if (t8) { pv[7] = pkb[7168 + tid]; gv[7] = gob[7168 + tid]; }

    const f32x4* fe4base = (const f32x4*)(fe + bc0 * NF);
    f32x4 a0, a1, a2, a3, b0, b1, b2, b3;

    // prologue: issue pair-0 loads (channels 0,1) — plain loads (L3 hits)
    {
        const f32x4* fA = fe4base;
        const f32x4* fB = fe4base + (NF / 4);
        a0 = fA[tid]; a1 = fA[tid + 1024]; a2 = fA[tid + 2048]; a3 = fA[tl];
        b0 = fB[tid]; b1 = fB[tid + 1024]; b2 = fB[tid + 2048]; b3 = fB[tl];
    }

#define PAIR_WRITE(S, VA, VB) do {                                       \
        fes32[(S).x & 0xFFFFu] = cvtpk((VA)[0], (VB)[0]);                \
        fes32[(S).x >> 16]     = cvtpk((VA)[1], (VB)[1]);                \
        fes32[(S).y & 0xFFFFu] = cvtpk((VA)[2], (VB)[2]);                \
        fes32[(S).y >> 16]     = cvtpk((VA)[3], (VB)[3]);                \
    } while (0)

// Paired gather: 8B LDS read (ds_read2_b32) = 2 members x 2 channels.
#define GATHER(P, GVI) do {                                              \
        uint p_ = (P);                                                   \
        uint off_ = p_ & 0x3FFFu, n_ = p_ >> 14;                         \
        float sa_ = 0.f, sb_ = 0.f;                                      \
        uint r_ = 0;                                                     \
        for (; r_ + 2 <= n_; r_ += 2) {                                  \
            uint2 w_;                                                    \
            __builtin_memcpy(&w_, &fes32[off_ + r_], 8);                 \
            sa_ += bf2f(w_.x & 0xFFFFu) + bf2f(w_.y & 0xFFFFu);          \
            sb_ += bf2f(w_.x >> 16) + bf2f(w_.y >> 16);                  \
        }                                                                \
        if (r_ < n_) {                                                   \
            uint w_ = fes32[off_ + r_];                                  \
            sa_ += bf2f(w_ & 0xFFFFu);                                   \
            sb_ += bf2f(w_ >> 16);                                       \
        }                                                                \
        float rn_ = n_ ? __builtin_amdgcn_rcpf((float)n_) : 0.f;         \
        outs[GVI] = sa_ * rn_;                                           \
        outs[NT + GVI] = sb_ * rn_;                                      \
    } while (0)

#pragma unroll
    for (int k = 0; k < CPB / 2; ++k) {
        // WRITE: consume current pair regs (progressive vmcnt waits)
        PAIR_WRITE(s0, a0, b0);
        PAIR_WRITE(s1, a1, b1);
        PAIR_WRITE(s2, a2, b2);
        if (t3) PAIR_WRITE(s3, a3, b3);

        // prefetch next pair: uniform 8 loads, in flight across the window
        if (k + 1 < CPB / 2) {
            const f32x4* fA = fe4base + (size_t)(2 * k + 2) * (NF / 4);
            const f32x4* fB = fA + (NF / 4);
            a0 = fA[tid]; a1 = fA[tid + 1024]; a2 = fA[tid + 2048]; a3 = fA[tl];
            b0 = fB[tid]; b1 = fB[tid + 1024]; b2 = fB[tid + 2048]; b3 = fB[tl];
        }

        LGKM_BAR();   // fes32 ready

        // P1: gather both channels per rank; scatter means to outs.
#pragma unroll
        for (int it = 0; it < 7; ++it) GATHER(pv[it], gv[it]);
        if (t8) GATHER(pv[7], gv[7]);

        LGKM_BAR();   // outs ready; fes32 fully consumed

        // FLUSH: coalesced NT f32x4, both channels. Uniform 4 stores/thread
        // (tail threads re-store element 0 — identical bytes, idempotent).
        {
            const f32x4* oa = (const f32x4*)outs;
            const f32x4* ob = (const f32x4*)(outs + NT);
            f32x4* oA = (f32x4*)(out + (bc0 + (size_t)(2 * k)) * NT);
            f32x4* oB = (f32x4*)(out + (bc0 + (size_t)(2 * k + 1)) * NT);
            f32x4 vA0 = oa[tid], vA1 = oa[fi];
            f32x4 vB0 = ob[tid], vB1 = ob[fi];
            __builtin_nontemporal_store(vA0, &oA[tid]);
            __builtin_nontemporal_store(vA1, &oA[fi]);
            __builtin_nontemporal_store(vB0, &oB[tid]);
            __builtin_nontemporal_store(vB1, &oB[fi]);
        }
    }
#undef GATHER
#undef PAIR_WRITE
}

// Fallback (round-2 path) if workspace is too small.
__device__ __forceinline__ void lds_fadd(unsigned addr, float v) {
    asm volatile("ds_add_f32 %0, %1" :: "v"(addr), "v"(v));
}
__global__ __launch_bounds__(256) void pool_fused_kernel(const float* __restrict__ fe,
                                                         const int* __restrict__ gid,
                                                         float* __restrict__ out) {
    __shared__ float acc[NT];
    __shared__ int cnt[NT];
    const int bc = blockIdx.x, b = bc >> 8, tid = threadIdx.x;
    for (int t = tid; t < NT; t += 256) { acc[t] = 0.0f; cnt[t] = 0; }
    __syncthreads();
    const unsigned accb = (unsigned)(uintptr_t)acc;
    const float4* fe4 = (const float4*)(fe + (size_t)bc * NF);
    const int4* gid4 = (const int4*)(gid + (size_t)b * NF);
    for (int i = tid; i < NF / 4; i += 256) {
        float4 v = fe4[i];
        int4 g = gid4[i];
        lds_fadd(accb + 4u * (unsigned)g.x, v.x); atomicAdd(&cnt[g.x], 1);
        lds_fadd(accb + 4u * (unsigned)g.y, v.y); atomicAdd(&cnt[g.y], 1);
        lds_fadd(accb + 4u * (unsigned)g.z, v.z); atomicAdd(&cnt[g.z], 1);
        lds_fadd(accb + 4u * (unsigned)g.w, v.w); atomicAdd(&cnt[g.w], 1);
    }
    asm volatile("s_waitcnt lgkmcnt(0)" ::: "memory");
    __syncthreads();
    float* orow = out + (size_t)bc * NT;
    for (int t = tid; t < NT; t += 256) {
        int n = cnt[t];
        orow[t] = acc[t] / (float)(n > 0 ? n : 1);
    }
}

extern "C" void kernel_launch(void* const* d_in, const int* in_sizes, int n_in,
                              void* d_out, int out_size, void* d_ws, size_t ws_size,
                              hipStream_t stream) {
    const float* fe = (const float*)d_in[0];
    const int* gid = (const int*)d_in[1];
    float* out = (float*)d_out;

    // workspace layout (bytes)
    const size_t O_CNT = 0;          // int [NB*NT]   512000
    const size_t O_CUR = 512000;     // u32 [NB*NT]   512000
    const size_t O_PK  = 1024000;    // u32 [NB*NT]   512000
    const size_t O_GO  = 1536000;    // u16 [NB*NT]   256000
    const size_t O_SP  = 1792000;    // u16 [NB*NF]   512000
    const size_t TOTAL = 2304000;

    if (ws_size >= TOTAL) {
        char* w = (char*)d_ws;
        int* cnt = (int*)(w + O_CNT);
        uint* cursor = (uint*)(w + O_CUR);
        uint* pk = (uint*)(w + O_PK);
        ushort* gorder = (ushort*)(w + O_GO);
        ushort* sp = (ushort*)(w + O_SP);

        static bool lds_opted = false;
        if (!lds_opted) {
            (void)hipFuncSetAttribute((const void*)pool_kernel,
                                      hipFuncAttributeMaxDynamicSharedMemorySize,
                                      128000);
            lds_opted = true;
        }

        (void)hipMemsetAsync(cnt, 0, 512000, stream);
        hist_kernel<<<(NB * NF / 4 + 255) / 256, 256, 0, stream>>>(gid, cnt);
        scan_rank_kernel<<<NB, 256, 0, stream>>>(cnt, pk, cursor, gorder);
        invperm_kernel<<<NB * 16, 256, 0, stream>>>(gid, cursor, sp);
        pool_kernel<<<NB * (NC / CPB), 1024, 128000, stream>>>(fe, sp, pk, gorder, out);
    } else {
        pool_fused_kernel<<<NB * NC, 256, 0, stream>>>(fe, gid, out);
    }
}